// Round 17
// baseline (216.102 us; speedup 1.0000x reference)
//
#include <hip/hip_runtime.h>
#include <hip/hip_bf16.h>

#define BB 2
#define NN 2048
#define KVN 2048
#define CC 1024
#define HH 16
#define HD 64

typedef __bf16 bf16;
typedef __attribute__((ext_vector_type(4))) __bf16 bf16x4;
typedef __attribute__((ext_vector_type(8))) __bf16 bf16x8;
typedef __attribute__((ext_vector_type(4))) float f32x4;

__device__ __forceinline__ void gload_lds16(const void* g, void* l) {
  __builtin_amdgcn_global_load_lds(
      (const __attribute__((address_space(1))) void*)g,
      (__attribute__((address_space(3))) void*)l, 16, 0, 0);
}

__device__ __forceinline__ float exp2_raw(float x) {
  float r;
  asm("v_exp_f32 %0, %1" : "=v"(r) : "v"(x));   // D = 2^S0, 1 VALU op
  return r;
}

// ---------------- fused prep: wtrans (1024 blk) + cvt_qkv (6144) + postab (512)
// All three are independent memory-bound preludes; one launch removes two
// full-drain sync points and overlaps their tails.
__global__ __launch_bounds__(256)
void prep(const float* __restrict__ qW, const float* __restrict__ kW,
          const float* __restrict__ vW, const float* __restrict__ pW,
          const float* __restrict__ q, const float* __restrict__ k,
          const float* __restrict__ v, const float* __restrict__ pos,
          bf16* __restrict__ Wt, bf16* __restrict__ Abf,
          float2* __restrict__ tab) {
  __shared__ bf16 t[64][72];
  const int bid = blockIdx.x, tid = threadIdx.x;
  if (bid < 1024) {
    // -------- wtrans: Wt[z][c][r] = (bf16)W_z[r][c]
    int z = bid >> 8, by = (bid >> 4) & 15, bx = bid & 15;
    const float* in = (z == 0) ? qW : (z == 1) ? kW : (z == 2) ? vW : pW;
    bf16* out = Wt + (size_t)z * CC * CC;
    int r0 = by * 64, c0 = bx * 64;
    int lr = tid >> 3, lc = (tid & 7) * 8;
    for (int p = 0; p < 2; ++p) {
      int rr = lr + p * 32;
      const float* src = &in[(size_t)(r0 + rr) * CC + c0 + lc];
      float4 a = *(const float4*)src;
      float4 b = *(const float4*)(src + 4);
      t[lc + 0][rr] = (bf16)a.x; t[lc + 1][rr] = (bf16)a.y;
      t[lc + 2][rr] = (bf16)a.z; t[lc + 3][rr] = (bf16)a.w;
      t[lc + 4][rr] = (bf16)b.x; t[lc + 5][rr] = (bf16)b.y;
      t[lc + 6][rr] = (bf16)b.z; t[lc + 7][rr] = (bf16)b.w;
    }
    __syncthreads();
    for (int p = 0; p < 2; ++p) {
      int rr = lr + p * 32;
      *(bf16x8*)&out[(size_t)(c0 + rr) * CC + r0 + lc] = *(const bf16x8*)&t[rr][lc];
    }
  } else if (bid < 7168) {
    // -------- cvt_qkv: fp32 -> bf16, Abf[z][row][col]
    int i = bid - 1024;
    int z = i >> 11, xb = i & 2047;
    const float* s = (z == 0) ? q : (z == 1) ? k : v;
    size_t off = ((size_t)xb * 256 + tid) * 8;
    float4 a = *(const float4*)(s + off);
    float4 b = *(const float4*)(s + off + 4);
    bf16x8 tt;
    tt[0] = (bf16)a.x; tt[1] = (bf16)a.y; tt[2] = (bf16)a.z; tt[3] = (bf16)a.w;
    tt[4] = (bf16)b.x; tt[5] = (bf16)b.y; tt[6] = (bf16)b.z; tt[7] = (bf16)b.w;
    *(bf16x8*)&Abf[(size_t)z * ((size_t)BB * NN * CC) + off] = tt;
  } else {
    // -------- postab: tab[l*HD+d] = (cos,sin)(pos[l][d]); 1 MB, L2-resident
    int i = (bid - 7168) * 256 + tid;
    float p = pos[i];
    float sn, cs;
    __sincosf(p, &sn, &cs);
    tab[i] = make_float2(cs, sn);
  }
}

// ---------------- merged QKV GEMM: 128x128 tile, BK=64 (round-8 v8 core).
// v11: both packs fused (rounds 14/15, verified) + RoPE via precomputed
// cos/sin table. z==0 folds log2(e) into scale for attn3's raw v_exp_f32.
__global__ __launch_bounds__(256, 3)
void gemm_qkv(const bf16* __restrict__ Abf, const bf16* __restrict__ Wt,
              const float2* __restrict__ tab, const int* __restrict__ mask,
              bf16* __restrict__ Qp, bf16* __restrict__ Kpack,
              bf16* __restrict__ Vpk, bf16* __restrict__ Mrow) {
  __shared__ bf16 As[128 * 64];   // 16 KB, chunks of 8: L = r*8 + (c^(r&7))
  __shared__ bf16 Bs[128 * 64];   // 16 KB, same swizzle
  const int bid = blockIdx.x;
  const int u = bid & 7, s = bid >> 3;       // s in [0,96)
  const int nblk = s >> 2;                   // 0..23
  const int m0 = (u * 4 + (s & 3)) * 128;
  const int z = nblk >> 3;
  const int n0 = (nblk & 7) * 128;
  const bf16* A = Abf + (size_t)z * ((size_t)BB * NN * CC);
  const bf16* Bt = Wt + (size_t)z * CC * CC;
  const int tid = threadIdx.x;
  const int wave = tid >> 6, lane = tid & 63;
  const int quad = lane >> 4, l15 = lane & 15;
  const int waveM = (wave >> 1) * 64, waveN = (wave & 1) * 64;
  f32x4 acc[4][4] = {};

  for (int k0 = 0; k0 < CC; k0 += 64) {
#pragma unroll
    for (int p = 0; p < 4; ++p) {   // B: 1024 bf16-chunks, async direct-to-LDS
      int ch = p * 256 + tid;
      int r = ch >> 3, c = (ch & 7) ^ (r & 7);
      gload_lds16(Bt + (size_t)(n0 + r) * CC + k0 + c * 8, &Bs[ch * 8]);
    }
#pragma unroll
    for (int p = 0; p < 4; ++p) {   // A: same proven path, bf16
      int ch = p * 256 + tid;
      int r = ch >> 3, c = (ch & 7) ^ (r & 7);
      gload_lds16(A + (size_t)(m0 + r) * CC + k0 + c * 8, &As[ch * 8]);
    }
    __syncthreads();
    bf16x8 af[4][2], bfr[4][2];
#pragma unroll
    for (int i = 0; i < 4; ++i) {
      int rA = waveM + i * 16 + l15;
      af[i][0] = *(const bf16x8*)&As[(rA * 8 + (quad ^ (rA & 7))) * 8];
      af[i][1] = *(const bf16x8*)&As[(rA * 8 + ((quad + 4) ^ (rA & 7))) * 8];
      int rB = waveN + i * 16 + l15;
      bfr[i][0] = *(const bf16x8*)&Bs[(rB * 8 + (quad ^ (rB & 7))) * 8];
      bfr[i][1] = *(const bf16x8*)&Bs[(rB * 8 + ((quad + 4) ^ (rB & 7))) * 8];
    }
#pragma unroll
    for (int mi = 0; mi < 4; ++mi)
#pragma unroll
      for (int ni = 0; ni < 4; ++ni) {
        acc[mi][ni] = __builtin_amdgcn_mfma_f32_16x16x32_bf16(
            af[mi][0], bfr[ni][0], acc[mi][ni], 0, 0, 0);
        acc[mi][ni] = __builtin_amdgcn_mfma_f32_16x16x32_bf16(
            af[mi][1], bfr[ni][1], acc[mi][ni], 0, 0, 0);
      }
    __syncthreads();
  }
  // epilogue: C/D col=lane&15, row=quad*4+reg
  const float scale = (z == 0) ? 0.125f * 1.44269504f : 1.0f;
  const int h2 = (n0 + waveN) >> 6;          // head for this wave's column group
  if (z == 2) {
    // ---- fused vpack: masked V^T A-frag scatter + mask row (round-15)
    const int row0 = m0 + waveM;             // 64-aligned; wave = one (b,tix)
    const int b2 = row0 >> 11;
    const int tixl = (row0 & (NN - 1)) >> 6;
    const int j0 = tixl * 64;
    const int bh = b2 * HH + h2;
    const int* maskb = mask + b2 * KVN;
    const size_t tb = (size_t)(bh * 32 + tixl) * 512;
#pragma unroll
    for (int mi = 0; mi < 4; ++mi) {
      int kl0 = mi * 16 + quad * 4;
      int mv0 = maskb[j0 + kl0 + 0], mv1 = maskb[j0 + kl0 + 1];
      int mv2 = maskb[j0 + kl0 + 2], mv3 = maskb[j0 + kl0 + 3];
      int hf = mi >> 1;
      int lane_v = ((mi & 1) * 2 + (quad >> 1)) * 16 + l15;
      int jj0 = (quad & 1) * 4;
#pragma unroll
      for (int ni = 0; ni < 4; ++ni) {
        int fs = ni * 2 + hf;
        bf16x4 ov;
        ov[0] = mv0 ? (bf16)acc[mi][ni][0] : (bf16)0.f;
        ov[1] = mv1 ? (bf16)acc[mi][ni][1] : (bf16)0.f;
        ov[2] = mv2 ? (bf16)acc[mi][ni][2] : (bf16)0.f;
        ov[3] = mv3 ? (bf16)acc[mi][ni][3] : (bf16)0.f;
        *(bf16x4*)&Vpk[(size_t)fs * (1 << 19) + tb + lane_v * 8 + jj0] = ov;
      }
    }
#pragma unroll
    for (int hf = 0; hf < 2; ++hf) {
      bf16x8 mv;
#pragma unroll
      for (int jj = 0; jj < 8; ++jj)
        mv[jj] = (l15 == 0) ? (bf16)(float)maskb[j0 + hf * 32 + quad * 8 + jj]
                            : (bf16)0.f;
      *(bf16x8*)&Mrow[(size_t)hf * (1 << 19) + tb + lane * 8] = mv;
    }
  } else {
#pragma unroll
    for (int mi = 0; mi < 4; ++mi) {
#pragma unroll
      for (int r = 0; r < 4; ++r) {
        int m = m0 + waveM + mi * 16 + quad * 4 + r;
        int l = m & (NN - 1);
        if (z == 0) {
#pragma unroll
          for (int ni = 0; ni < 2; ++ni) {
            int col = n0 + waveN + ni * 16 + l15;
            int d = ni * 16 + l15;               // head-local, in [0,32)
            float x1 = acc[mi][ni][r], x2 = acc[mi][ni + 2][r];
            float2 cs1 = tab[l * HD + d];
            float2 cs2 = tab[l * HD + d + 32];
            Qp[(size_t)m * CC + col]      = (bf16)((x1 * cs1.x - x2 * cs1.y) * scale);
            Qp[(size_t)m * CC + col + 32] = (bf16)((x2 * cs2.x + x1 * cs2.y) * scale);
          }
        } else {  // z == 1: RoPE + direct Kpack scatter (round-14 verified)
          int key = l;
          int bb2 = m >> 11;
          size_t kb_ = ((((size_t)(bb2 * HH + h2)) * 32 + (key >> 6)) * 8
                        + ((key >> 4) & 3) * 2) * 512 + (size_t)(key & 15) * 8;
#pragma unroll
          for (int ni = 0; ni < 2; ++ni) {
            int d = ni * 16 + l15;               // in [0,32); pair at d+32
            float x1 = acc[mi][ni][r], x2 = acc[mi][ni + 2][r];
            float2 cs1 = tab[l * HD + d];
            float2 cs2 = tab[l * HD + d + 32];
            size_t off = kb_ + ((d >> 3) & 3) * 128 + (d & 7);
            Kpack[off]       = (bf16)(x1 * cs1.x - x2 * cs1.y);    // d
            Kpack[off + 512] = (bf16)(x2 * cs2.x + x1 * cs2.y);    // d+32
          }
        }
      }
    }
  }
}

// ---------------- attention v8: round-13 structure + P-slab restride 128B->
// 144B/row. Old stride: l15*128 == 0 mod 32 banks -> all 16 q-rows aliased
// the same banks (stores 4-way, reads up to 8-way; measured 2.1M conflict
// cycles ~7%). 144B keeps 16B alignment for ds_read_b128 and shifts each row
// by 4 banks -> ~2-way (free, m136). Within-row slot layout unchanged.
// P region 4x2304=9216B, merge 40960B -> smem 50176 (2 blocks x 50K <= 160K).
__global__ __launch_bounds__(256, 2)
void attn3(const bf16* __restrict__ Qp, const bf16* __restrict__ Kpack,
           const bf16* __restrict__ Vpk, const bf16* __restrict__ Mrow,
           bf16* __restrict__ X) {
  __shared__ char smem[50176];      // [0,9216): per-wave P; [9216,...): merge
  const int tid = threadIdx.x, wave = tid >> 6, lane = tid & 63;
  const int quad = lane >> 4, l15 = lane & 15;
  const int bid = blockIdx.x;
  const int u = bid & 7, s = bid >> 3;
  const int bh = u * 4 + (s & 3), qp = s >> 2;
  const int b = bh >> 4, h = bh & 15;
  const int qc = qp * 2 + (wave >> 1), kh = wave & 1;
  const int q0 = qc * 64;
  const int sw = 2 * (l15 & 7);

  char* P = smem + wave * 2304;     // 16 rows x 144 B
  float* mrg = (float*)(smem + 9216);

  bf16x8 qa[4][2];
#pragma unroll
  for (int g = 0; g < 4; ++g) {
    const bf16* qrow = Qp + ((size_t)(b * NN) + q0 + g * 16 + l15) * CC + h * HD;
    qa[g][0] = *(const bf16x8*)&qrow[quad * 8];
    qa[g][1] = *(const bf16x8*)&qrow[32 + quad * 8];
  }

  f32x4 Oacc[4][5] = {};
  const bf16* kbase = Kpack + (size_t)bh * 32 * 8 * 512;

  for (int it = 0; it < 16; ++it) {
    int t = kh * 16 + it;
    bf16x8 kb[8], vb[10];
#pragma unroll
    for (int fs = 0; fs < 8; ++fs)
      kb[fs] = *(const bf16x8*)&kbase[((size_t)t * 8 + fs) * 512 + lane * 8];
#pragma unroll
    for (int fs = 0; fs < 10; ++fs) {
      const bf16* vbs = (fs < 8) ? (Vpk + (size_t)fs * (1 << 19))
                                 : (Mrow + (size_t)(fs - 8) * (1 << 19));
      vb[fs] = *(const bf16x8*)&vbs[((size_t)(bh * 32 + t)) * 512 + lane * 8];
    }
#pragma unroll
    for (int g = 0; g < 4; ++g) {
      f32x4 sg[4];
      __builtin_amdgcn_s_setprio(1);
#pragma unroll
      for (int ni = 0; ni < 4; ++ni) {
        f32x4 zz = {};
        zz = __builtin_amdgcn_mfma_f32_16x16x32_bf16(kb[ni * 2], qa[g][0], zz, 0, 0, 0);
        zz = __builtin_amdgcn_mfma_f32_16x16x32_bf16(kb[ni * 2 + 1], qa[g][1], zz, 0, 0, 0);
        sg[ni] = zz;
      }
      __builtin_amdgcn_s_setprio(0);
#pragma unroll
      for (int ni = 0; ni < 4; ++ni) {
        bf16x4 pk;
#pragma unroll
        for (int r = 0; r < 4; ++r) pk[r] = (bf16)exp2_raw(sg[ni][r] - 5.7707802f);
        *(bf16x4*)&P[l15 * 144 + (((ni * 4 + quad) ^ sw)) * 8] = pk;
      }
      bf16x8 pf0 = *(const bf16x8*)&P[l15 * 144 + (((quad * 2) ^ sw)) * 8];
      bf16x8 pf1 = *(const bf16x8*)&P[l15 * 144 + (((8 + quad * 2) ^ sw)) * 8];
      __builtin_amdgcn_s_setprio(1);
#pragma unroll
      for (int ni = 0; ni < 5; ++ni) {
        Oacc[g][ni] = __builtin_amdgcn_mfma_f32_16x16x32_bf16(vb[ni * 2], pf0, Oacc[g][ni], 0, 0, 0);
        Oacc[g][ni] = __builtin_amdgcn_mfma_f32_16x16x32_bf16(vb[ni * 2 + 1], pf1, Oacc[g][ni], 0, 0, 0);
      }
      __builtin_amdgcn_s_setprio(0);
    }
  }
  if (kh == 1) {
    float* dst = mrg + (wave >> 1) * 5120 + lane * 4;
#pragma unroll
    for (int g = 0; g < 4; ++g)
#pragma unroll
      for (int ni = 0; ni < 5; ++ni)
        *(f32x4*)&dst[(g * 5 + ni) * 256] = Oacc[g][ni];
  }
  __syncthreads();
  if (kh == 0) {
    float* src = mrg + (wave >> 1) * 5120 + lane * 4;
#pragma unroll
    for (int g = 0; g < 4; ++g) {
#pragma unroll
      for (int ni = 0; ni < 5; ++ni) {
        f32x4 o = *(const f32x4*)&src[(g * 5 + ni) * 256];
#pragma unroll
        for (int r = 0; r < 4; ++r) Oacc[g][ni][r] += o[r];
      }
      float ls = __shfl(Oacc[g][4][0], l15, 64);
      float rn = 1.0f / ls;
#pragma unroll
      for (int ni = 0; ni < 4; ++ni) {
        bf16x4 ov;
#pragma unroll
        for (int r = 0; r < 4; ++r) ov[r] = (bf16)(Oacc[g][ni][r] * rn);
        *(bf16x4*)&X[((size_t)(b * NN) + q0 + g * 16 + l15) * CC
                     + h * HD + ni * 16 + quad * 4] = ov;
      }
    }
  }
}

// ---------------- projection GEMM: 64x128 tile, BK=64, 8-slot swizzle, grid 512
__global__ __launch_bounds__(256, 4)
void gemm_proj(const bf16* __restrict__ A, const bf16* __restrict__ Bt,
               float* __restrict__ Out) {
  __shared__ bf16 As[64 * 64];    // 8 KB
  __shared__ bf16 Bs[128 * 64];   // 16 KB
  const int bid = blockIdx.x;
  const int u = bid & 7, s = bid >> 3;        // s in [0,64)
  const int m0 = (u * 8 + (s >> 3)) * 64;
  const int n0 = (s & 7) * 128;
  const int tid = threadIdx.x;
  const int wave = tid >> 6, lane = tid & 63;
  const int quad = lane >> 4, l15 = lane & 15;
  const int waveM = (wave >> 1) * 32, waveN = (wave & 1) * 64;
  f32x4 acc[2][4] = {};

  for (int k0 = 0; k0 < CC; k0 += 64) {
#pragma unroll
    for (int p = 0; p < 2; ++p) {
      int ch = p * 256 + tid;
      int r = ch >> 3, c = (ch & 7) ^ (r & 7);
      gload_lds16(A + (size_t)(m0 + r) * CC + k0 + c * 8, &As[ch * 8]);
    }
#pragma unroll
    for (int p = 0; p < 4; ++p) {
      int ch = p * 256 + tid;
      int r = ch >> 3, c = (ch & 7) ^ (r & 7);
      gload_lds16(Bt + (size_t)(n0 + r) * CC + k0 + c * 8, &Bs[ch * 8]);
    }
    __syncthreads();
    bf16x8 af[2][2], bfr[4][2];
#pragma unroll
    for (int i = 0; i < 2; ++i) {
      int rA = waveM + i * 16 + l15;
      af[i][0] = *(const bf16x8*)&As[(rA * 8 + (quad ^ (rA & 7))) * 8];
      af[i][1] = *(const bf16x8*)&As[(rA * 8 + ((quad + 4) ^ (rA & 7))) * 8];
    }
#pragma unroll
    for (int i = 0; i < 4; ++i) {
      int rB = waveN + i * 16 + l15;
      bfr[i][0] = *(const bf16x8*)&Bs[(rB * 8 + (quad ^ (rB & 7))) * 8];
      bfr[i][1] = *(const bf16x8*)&Bs[(rB * 8 + ((quad + 4) ^ (rB & 7))) * 8];
    }
#pragma unroll
    for (int mi = 0; mi < 2; ++mi)
#pragma unroll
      for (int ni = 0; ni < 4; ++ni) {
        acc[mi][ni] = __builtin_amdgcn_mfma_f32_16x16x32_bf16(
            af[mi][0], bfr[ni][0], acc[mi][ni], 0, 0, 0);
        acc[mi][ni] = __builtin_amdgcn_mfma_f32_16x16x32_bf16(
            af[mi][1], bfr[ni][1], acc[mi][ni], 0, 0, 0);
      }
    __syncthreads();
  }
#pragma unroll
  for (int mi = 0; mi < 2; ++mi)
#pragma unroll
    for (int ni = 0; ni < 4; ++ni)
#pragma unroll
      for (int r = 0; r < 4; ++r) {
        int row = m0 + waveM + mi * 16 + quad * 4 + r;
        int col = n0 + waveN + ni * 16 + l15;
        Out[(size_t)row * CC + col] = acc[mi][ni][r];
      }
}

extern "C" void kernel_launch(void* const* d_in, const int* in_sizes, int n_in,
                              void* d_out, int out_size, void* d_ws, size_t ws_size,
                              hipStream_t stream) {
  const float* q    = (const float*)d_in[0];
  const float* k    = (const float*)d_in[1];
  const float* v    = (const float*)d_in[2];
  const int*   mask = (const int*)d_in[3];
  const float* pos  = (const float*)d_in[4];
  const float* qW   = (const float*)d_in[5];
  const float* kW   = (const float*)d_in[6];
  const float* vW   = (const float*)d_in[7];
  const float* pW   = (const float*)d_in[8];
  float* out = (float*)d_out;

  char* w = (char*)d_ws;
  const size_t MB = 1024 * 1024;
  // layout (59MB peak; proven round 16):
  //   Wt@0-8     (pWt@6-8 live to gemm_proj)
  //   Qp@8-16    (gemm_qkv -> attn3)
  //   Kpack@16-24 (gemm_qkv z==1 -> attn3)
  //   Vpk@24-32  (gemm_qkv z==2 -> attn3; V^T frags fs0-7, 1MB stride)
  //   Abf@32-56  (prep -> gemm_qkv, dead after)
  //   Mrow@56-58 (gemm_qkv z==2 -> attn3; mask rows fs8,9)
  //   Ptab@58-59 (prep -> gemm_qkv; RoPE cos/sin float2 table)
  //   X@32-40    over dead Abf head (attn3 -> gemm_proj)
  bf16*   Wt    = (bf16*)(w);
  bf16*   Qp    = (bf16*)(w + 8 * MB);
  bf16*   Kpack = (bf16*)(w + 16 * MB);
  bf16*   Vpk   = (bf16*)(w + 24 * MB);
  bf16*   Abf   = (bf16*)(w + 32 * MB);
  bf16*   Mrow  = (bf16*)(w + 56 * MB);
  float2* Ptab  = (float2*)(w + 58 * MB);
  bf16*   X     = (bf16*)(w + 32 * MB);

  prep<<<dim3(7680), 256, 0, stream>>>(qW, kW, vW, pW, q, k, v, pos,
                                       Wt, Abf, Ptab);
  gemm_qkv<<<dim3(768), 256, 0, stream>>>(Abf, Wt, Ptab, mask, Qp, Kpack, Vpk, Mrow);
  attn3<<<dim3(512), 256, 0, stream>>>(Qp, Kpack, Vpk, Mrow, X);
  gemm_proj<<<dim3(512), 256, 0, stream>>>(X, Wt + 3 * (size_t)CC * CC, out);
}

// Round 18
// 197.053 us; speedup vs baseline: 1.0967x; 1.0967x over previous
//
#include <hip/hip_runtime.h>
#include <hip/hip_bf16.h>

#define BB 2
#define NN 2048
#define KVN 2048
#define CC 1024
#define HH 16
#define HD 64

typedef __bf16 bf16;
typedef __attribute__((ext_vector_type(4))) __bf16 bf16x4;
typedef __attribute__((ext_vector_type(8))) __bf16 bf16x8;
typedef __attribute__((ext_vector_type(4))) float f32x4;

__device__ __forceinline__ void gload_lds16(const void* g, void* l) {
  __builtin_amdgcn_global_load_lds(
      (const __attribute__((address_space(1))) void*)g,
      (__attribute__((address_space(3))) void*)l, 16, 0, 0);
}

__device__ __forceinline__ float exp2_raw(float x) {
  float r;
  asm("v_exp_f32 %0, %1" : "=v"(r) : "v"(x));   // D = 2^S0, 1 VALU op
  return r;
}

// ---------------- fused prep: wtrans (1024 blk) + cvt_qkv (6144) + postab (512)
__global__ __launch_bounds__(256)
void prep(const float* __restrict__ qW, const float* __restrict__ kW,
          const float* __restrict__ vW, const float* __restrict__ pW,
          const float* __restrict__ q, const float* __restrict__ k,
          const float* __restrict__ v, const float* __restrict__ pos,
          bf16* __restrict__ Wt, bf16* __restrict__ Abf,
          float2* __restrict__ tab) {
  __shared__ bf16 t[64][72];
  const int bid = blockIdx.x, tid = threadIdx.x;
  if (bid < 1024) {
    // -------- wtrans: Wt[z][c][r] = (bf16)W_z[r][c]
    int z = bid >> 8, by = (bid >> 4) & 15, bx = bid & 15;
    const float* in = (z == 0) ? qW : (z == 1) ? kW : (z == 2) ? vW : pW;
    bf16* out = Wt + (size_t)z * CC * CC;
    int r0 = by * 64, c0 = bx * 64;
    int lr = tid >> 3, lc = (tid & 7) * 8;
    for (int p = 0; p < 2; ++p) {
      int rr = lr + p * 32;
      const float* src = &in[(size_t)(r0 + rr) * CC + c0 + lc];
      float4 a = *(const float4*)src;
      float4 b = *(const float4*)(src + 4);
      t[lc + 0][rr] = (bf16)a.x; t[lc + 1][rr] = (bf16)a.y;
      t[lc + 2][rr] = (bf16)a.z; t[lc + 3][rr] = (bf16)a.w;
      t[lc + 4][rr] = (bf16)b.x; t[lc + 5][rr] = (bf16)b.y;
      t[lc + 6][rr] = (bf16)b.z; t[lc + 7][rr] = (bf16)b.w;
    }
    __syncthreads();
    for (int p = 0; p < 2; ++p) {
      int rr = lr + p * 32;
      *(bf16x8*)&out[(size_t)(c0 + rr) * CC + r0 + lc] = *(const bf16x8*)&t[rr][lc];
    }
  } else if (bid < 7168) {
    // -------- cvt_qkv: fp32 -> bf16, Abf[z][row][col]
    int i = bid - 1024;
    int z = i >> 11, xb = i & 2047;
    const float* s = (z == 0) ? q : (z == 1) ? k : v;
    size_t off = ((size_t)xb * 256 + tid) * 8;
    float4 a = *(const float4*)(s + off);
    float4 b = *(const float4*)(s + off + 4);
    bf16x8 tt;
    tt[0] = (bf16)a.x; tt[1] = (bf16)a.y; tt[2] = (bf16)a.z; tt[3] = (bf16)a.w;
    tt[4] = (bf16)b.x; tt[5] = (bf16)b.y; tt[6] = (bf16)b.z; tt[7] = (bf16)b.w;
    *(bf16x8*)&Abf[(size_t)z * ((size_t)BB * NN * CC) + off] = tt;
  } else {
    // -------- postab: tab[l*HD+d] = (cos,sin)(pos[l][d]); 1 MB, L2-resident
    int i = (bid - 7168) * 256 + tid;
    float p = pos[i];
    float sn, cs;
    __sincosf(p, &sn, &cs);
    tab[i] = make_float2(cs, sn);
  }
}

// ---------------- merged QKV GEMM: 128x128 tile, BK=64 (round-8 v8 core).
// v11: both packs fused (rounds 14/15, verified) + RoPE via precomputed
// cos/sin table. z==0 folds log2(e) into scale for attn3's raw v_exp_f32.
__global__ __launch_bounds__(256, 3)
void gemm_qkv(const bf16* __restrict__ Abf, const bf16* __restrict__ Wt,
              const float2* __restrict__ tab, const int* __restrict__ mask,
              bf16* __restrict__ Qp, bf16* __restrict__ Kpack,
              bf16* __restrict__ Vpk, bf16* __restrict__ Mrow) {
  __shared__ bf16 As[128 * 64];   // 16 KB, chunks of 8: L = r*8 + (c^(r&7))
  __shared__ bf16 Bs[128 * 64];   // 16 KB, same swizzle
  const int bid = blockIdx.x;
  const int u = bid & 7, s = bid >> 3;       // s in [0,96)
  const int nblk = s >> 2;                   // 0..23
  const int m0 = (u * 4 + (s & 3)) * 128;
  const int z = nblk >> 3;
  const int n0 = (nblk & 7) * 128;
  const bf16* A = Abf + (size_t)z * ((size_t)BB * NN * CC);
  const bf16* Bt = Wt + (size_t)z * CC * CC;
  const int tid = threadIdx.x;
  const int wave = tid >> 6, lane = tid & 63;
  const int quad = lane >> 4, l15 = lane & 15;
  const int waveM = (wave >> 1) * 64, waveN = (wave & 1) * 64;
  f32x4 acc[4][4] = {};

  for (int k0 = 0; k0 < CC; k0 += 64) {
#pragma unroll
    for (int p = 0; p < 4; ++p) {   // B: 1024 bf16-chunks, async direct-to-LDS
      int ch = p * 256 + tid;
      int r = ch >> 3, c = (ch & 7) ^ (r & 7);
      gload_lds16(Bt + (size_t)(n0 + r) * CC + k0 + c * 8, &Bs[ch * 8]);
    }
#pragma unroll
    for (int p = 0; p < 4; ++p) {   // A: same proven path, bf16
      int ch = p * 256 + tid;
      int r = ch >> 3, c = (ch & 7) ^ (r & 7);
      gload_lds16(A + (size_t)(m0 + r) * CC + k0 + c * 8, &As[ch * 8]);
    }
    __syncthreads();
    bf16x8 af[4][2], bfr[4][2];
#pragma unroll
    for (int i = 0; i < 4; ++i) {
      int rA = waveM + i * 16 + l15;
      af[i][0] = *(const bf16x8*)&As[(rA * 8 + (quad ^ (rA & 7))) * 8];
      af[i][1] = *(const bf16x8*)&As[(rA * 8 + ((quad + 4) ^ (rA & 7))) * 8];
      int rB = waveN + i * 16 + l15;
      bfr[i][0] = *(const bf16x8*)&Bs[(rB * 8 + (quad ^ (rB & 7))) * 8];
      bfr[i][1] = *(const bf16x8*)&Bs[(rB * 8 + ((quad + 4) ^ (rB & 7))) * 8];
    }
#pragma unroll
    for (int mi = 0; mi < 4; ++mi)
#pragma unroll
      for (int ni = 0; ni < 4; ++ni) {
        acc[mi][ni] = __builtin_amdgcn_mfma_f32_16x16x32_bf16(
            af[mi][0], bfr[ni][0], acc[mi][ni], 0, 0, 0);
        acc[mi][ni] = __builtin_amdgcn_mfma_f32_16x16x32_bf16(
            af[mi][1], bfr[ni][1], acc[mi][ni], 0, 0, 0);
      }
    __syncthreads();
  }
  // epilogue: C/D col=lane&15, row=quad*4+reg
  const float scale = (z == 0) ? 0.125f * 1.44269504f : 1.0f;
  const int h2 = (n0 + waveN) >> 6;          // head for this wave's column group
  if (z == 2) {
    // ---- fused vpack: masked V^T A-frag scatter + mask row (round-15)
    const int row0 = m0 + waveM;             // 64-aligned; wave = one (b,tix)
    const int b2 = row0 >> 11;
    const int tixl = (row0 & (NN - 1)) >> 6;
    const int j0 = tixl * 64;
    const int bh = b2 * HH + h2;
    const int* maskb = mask + b2 * KVN;
    const size_t tb = (size_t)(bh * 32 + tixl) * 512;
#pragma unroll
    for (int mi = 0; mi < 4; ++mi) {
      int kl0 = mi * 16 + quad * 4;
      int mv0 = maskb[j0 + kl0 + 0], mv1 = maskb[j0 + kl0 + 1];
      int mv2 = maskb[j0 + kl0 + 2], mv3 = maskb[j0 + kl0 + 3];
      int hf = mi >> 1;
      int lane_v = ((mi & 1) * 2 + (quad >> 1)) * 16 + l15;
      int jj0 = (quad & 1) * 4;
#pragma unroll
      for (int ni = 0; ni < 4; ++ni) {
        int fs = ni * 2 + hf;
        bf16x4 ov;
        ov[0] = mv0 ? (bf16)acc[mi][ni][0] : (bf16)0.f;
        ov[1] = mv1 ? (bf16)acc[mi][ni][1] : (bf16)0.f;
        ov[2] = mv2 ? (bf16)acc[mi][ni][2] : (bf16)0.f;
        ov[3] = mv3 ? (bf16)acc[mi][ni][3] : (bf16)0.f;
        *(bf16x4*)&Vpk[(size_t)fs * (1 << 19) + tb + lane_v * 8 + jj0] = ov;
      }
    }
#pragma unroll
    for (int hf = 0; hf < 2; ++hf) {
      bf16x8 mv;
#pragma unroll
      for (int jj = 0; jj < 8; ++jj)
        mv[jj] = (l15 == 0) ? (bf16)(float)maskb[j0 + hf * 32 + quad * 8 + jj]
                            : (bf16)0.f;
      *(bf16x8*)&Mrow[(size_t)hf * (1 << 19) + tb + lane * 8] = mv;
    }
  } else {
#pragma unroll
    for (int mi = 0; mi < 4; ++mi) {
#pragma unroll
      for (int r = 0; r < 4; ++r) {
        int m = m0 + waveM + mi * 16 + quad * 4 + r;
        int l = m & (NN - 1);
        if (z == 0) {
#pragma unroll
          for (int ni = 0; ni < 2; ++ni) {
            int col = n0 + waveN + ni * 16 + l15;
            int d = ni * 16 + l15;               // head-local, in [0,32)
            float x1 = acc[mi][ni][r], x2 = acc[mi][ni + 2][r];
            float2 cs1 = tab[l * HD + d];
            float2 cs2 = tab[l * HD + d + 32];
            Qp[(size_t)m * CC + col]      = (bf16)((x1 * cs1.x - x2 * cs1.y) * scale);
            Qp[(size_t)m * CC + col + 32] = (bf16)((x2 * cs2.x + x1 * cs2.y) * scale);
          }
        } else {  // z == 1: RoPE + direct Kpack scatter (round-14 verified)
          int key = l;
          int bb2 = m >> 11;
          size_t kb_ = ((((size_t)(bb2 * HH + h2)) * 32 + (key >> 6)) * 8
                        + ((key >> 4) & 3) * 2) * 512 + (size_t)(key & 15) * 8;
#pragma unroll
          for (int ni = 0; ni < 2; ++ni) {
            int d = ni * 16 + l15;               // in [0,32); pair at d+32
            float x1 = acc[mi][ni][r], x2 = acc[mi][ni + 2][r];
            float2 cs1 = tab[l * HD + d];
            float2 cs2 = tab[l * HD + d + 32];
            size_t off = kb_ + ((d >> 3) & 3) * 128 + (d & 7);
            Kpack[off]       = (bf16)(x1 * cs1.x - x2 * cs1.y);    // d
            Kpack[off + 512] = (bf16)(x2 * cs2.x + x1 * cs2.y);    // d+32
          }
        }
      }
    }
  }
}

// ---------------- attention v7 (round-16 exact, measured 47.0-48.6us): grid
// 512, 2qc x 2kh waves, 16 iters, single parallel merge, base-2 softmax via
// raw v_exp_f32, setprio. P layout 128B/row RESTORED: round-17 postmortem
// showed the 144B restride created 8-way conflicts (18.9M, 9x) -- the 128B
// layout's 16 slots map 1:1 onto all 32 banks at exactly 4 accesses each,
// which is the hardware floor for 64x8B stores. P-conflict lever closed.
__global__ __launch_bounds__(256, 2)
void attn3(const bf16* __restrict__ Qp, const bf16* __restrict__ Kpack,
           const bf16* __restrict__ Vpk, const bf16* __restrict__ Mrow,
           bf16* __restrict__ X) {
  __shared__ char smem[49152];      // [0,8K): per-wave P; [8K,48K): merge buffer
  const int tid = threadIdx.x, wave = tid >> 6, lane = tid & 63;
  const int quad = lane >> 4, l15 = lane & 15;
  const int bid = blockIdx.x;
  const int u = bid & 7, s = bid >> 3;
  const int bh = u * 4 + (s & 3), qp = s >> 2;
  const int b = bh >> 4, h = bh & 15;
  const int qc = qp * 2 + (wave >> 1), kh = wave & 1;
  const int q0 = qc * 64;
  const int sw = 2 * (l15 & 7);

  bf16* P = (bf16*)(smem + wave * 2048);
  float* mrg = (float*)(smem + 8192);

  bf16x8 qa[4][2];
#pragma unroll
  for (int g = 0; g < 4; ++g) {
    const bf16* qrow = Qp + ((size_t)(b * NN) + q0 + g * 16 + l15) * CC + h * HD;
    qa[g][0] = *(const bf16x8*)&qrow[quad * 8];
    qa[g][1] = *(const bf16x8*)&qrow[32 + quad * 8];
  }

  f32x4 Oacc[4][5] = {};
  const bf16* kbase = Kpack + (size_t)bh * 32 * 8 * 512;

  for (int it = 0; it < 16; ++it) {
    int t = kh * 16 + it;
    bf16x8 kb[8], vb[10];
#pragma unroll
    for (int fs = 0; fs < 8; ++fs)
      kb[fs] = *(const bf16x8*)&kbase[((size_t)t * 8 + fs) * 512 + lane * 8];
#pragma unroll
    for (int fs = 0; fs < 10; ++fs) {
      const bf16* vbs = (fs < 8) ? (Vpk + (size_t)fs * (1 << 19))
                                 : (Mrow + (size_t)(fs - 8) * (1 << 19));
      vb[fs] = *(const bf16x8*)&vbs[((size_t)(bh * 32 + t)) * 512 + lane * 8];
    }
#pragma unroll
    for (int g = 0; g < 4; ++g) {
      f32x4 sg[4];
      __builtin_amdgcn_s_setprio(1);
#pragma unroll
      for (int ni = 0; ni < 4; ++ni) {
        f32x4 zz = {};
        zz = __builtin_amdgcn_mfma_f32_16x16x32_bf16(kb[ni * 2], qa[g][0], zz, 0, 0, 0);
        zz = __builtin_amdgcn_mfma_f32_16x16x32_bf16(kb[ni * 2 + 1], qa[g][1], zz, 0, 0, 0);
        sg[ni] = zz;
      }
      __builtin_amdgcn_s_setprio(0);
#pragma unroll
      for (int ni = 0; ni < 4; ++ni) {
        bf16x4 pk;
#pragma unroll
        for (int r = 0; r < 4; ++r) pk[r] = (bf16)exp2_raw(sg[ni][r] - 5.7707802f);
        *(bf16x4*)&P[(l15 * 16 + ((ni * 4 + quad) ^ sw)) * 4] = pk;
      }
      bf16x8 pf0 = *(const bf16x8*)&P[(l15 * 16 + ((quad * 2) ^ sw)) * 4];
      bf16x8 pf1 = *(const bf16x8*)&P[(l15 * 16 + ((8 + quad * 2) ^ sw)) * 4];
      __builtin_amdgcn_s_setprio(1);
#pragma unroll
      for (int ni = 0; ni < 5; ++ni) {
        Oacc[g][ni] = __builtin_amdgcn_mfma_f32_16x16x32_bf16(vb[ni * 2], pf0, Oacc[g][ni], 0, 0, 0);
        Oacc[g][ni] = __builtin_amdgcn_mfma_f32_16x16x32_bf16(vb[ni * 2 + 1], pf1, Oacc[g][ni], 0, 0, 0);
      }
      __builtin_amdgcn_s_setprio(0);
    }
  }
  if (kh == 1) {
    float* dst = mrg + (wave >> 1) * 5120 + lane * 4;
#pragma unroll
    for (int g = 0; g < 4; ++g)
#pragma unroll
      for (int ni = 0; ni < 5; ++ni)
        *(f32x4*)&dst[(g * 5 + ni) * 256] = Oacc[g][ni];
  }
  __syncthreads();
  if (kh == 0) {
    float* src = mrg + (wave >> 1) * 5120 + lane * 4;
#pragma unroll
    for (int g = 0; g < 4; ++g) {
#pragma unroll
      for (int ni = 0; ni < 5; ++ni) {
        f32x4 o = *(const f32x4*)&src[(g * 5 + ni) * 256];
#pragma unroll
        for (int r = 0; r < 4; ++r) Oacc[g][ni][r] += o[r];
      }
      float ls = __shfl(Oacc[g][4][0], l15, 64);
      float rn = 1.0f / ls;
#pragma unroll
      for (int ni = 0; ni < 4; ++ni) {
        bf16x4 ov;
#pragma unroll
        for (int r = 0; r < 4; ++r) ov[r] = (bf16)(Oacc[g][ni][r] * rn);
        *(bf16x4*)&X[((size_t)(b * NN) + q0 + g * 16 + l15) * CC
                     + h * HD + ni * 16 + quad * 4] = ov;
      }
    }
  }
}

// ---------------- projection GEMM: 64x128 tile, BK=64, 8-slot swizzle, grid 512
__global__ __launch_bounds__(256, 4)
void gemm_proj(const bf16* __restrict__ A, const bf16* __restrict__ Bt,
               float* __restrict__ Out) {
  __shared__ bf16 As[64 * 64];    // 8 KB
  __shared__ bf16 Bs[128 * 64];   // 16 KB
  const int bid = blockIdx.x;
  const int u = bid & 7, s = bid >> 3;        // s in [0,64)
  const int m0 = (u * 8 + (s >> 3)) * 64;
  const int n0 = (s & 7) * 128;
  const int tid = threadIdx.x;
  const int wave = tid >> 6, lane = tid & 63;
  const int quad = lane >> 4, l15 = lane & 15;
  const int waveM = (wave >> 1) * 32, waveN = (wave & 1) * 64;
  f32x4 acc[2][4] = {};

  for (int k0 = 0; k0 < CC; k0 += 64) {
#pragma unroll
    for (int p = 0; p < 2; ++p) {
      int ch = p * 256 + tid;
      int r = ch >> 3, c = (ch & 7) ^ (r & 7);
      gload_lds16(A + (size_t)(m0 + r) * CC + k0 + c * 8, &As[ch * 8]);
    }
#pragma unroll
    for (int p = 0; p < 4; ++p) {
      int ch = p * 256 + tid;
      int r = ch >> 3, c = (ch & 7) ^ (r & 7);
      gload_lds16(Bt + (size_t)(n0 + r) * CC + k0 + c * 8, &Bs[ch * 8]);
    }
    __syncthreads();
    bf16x8 af[2][2], bfr[4][2];
#pragma unroll
    for (int i = 0; i < 2; ++i) {
      int rA = waveM + i * 16 + l15;
      af[i][0] = *(const bf16x8*)&As[(rA * 8 + (quad ^ (rA & 7))) * 8];
      af[i][1] = *(const bf16x8*)&As[(rA * 8 + ((quad + 4) ^ (rA & 7))) * 8];
    }
#pragma unroll
    for (int i = 0; i < 4; ++i) {
      int rB = waveN + i * 16 + l15;
      bfr[i][0] = *(const bf16x8*)&Bs[(rB * 8 + (quad ^ (rB & 7))) * 8];
      bfr[i][1] = *(const bf16x8*)&Bs[(rB * 8 + ((quad + 4) ^ (rB & 7))) * 8];
    }
#pragma unroll
    for (int mi = 0; mi < 2; ++mi)
#pragma unroll
      for (int ni = 0; ni < 4; ++ni) {
        acc[mi][ni] = __builtin_amdgcn_mfma_f32_16x16x32_bf16(
            af[mi][0], bfr[ni][0], acc[mi][ni], 0, 0, 0);
        acc[mi][ni] = __builtin_amdgcn_mfma_f32_16x16x32_bf16(
            af[mi][1], bfr[ni][1], acc[mi][ni], 0, 0, 0);
      }
    __syncthreads();
  }
#pragma unroll
  for (int mi = 0; mi < 2; ++mi)
#pragma unroll
    for (int ni = 0; ni < 4; ++ni)
#pragma unroll
      for (int r = 0; r < 4; ++r) {
        int row = m0 + waveM + mi * 16 + quad * 4 + r;
        int col = n0 + waveN + ni * 16 + l15;
        Out[(size_t)row * CC + col] = acc[mi][ni][r];
      }
}

extern "C" void kernel_launch(void* const* d_in, const int* in_sizes, int n_in,
                              void* d_out, int out_size, void* d_ws, size_t ws_size,
                              hipStream_t stream) {
  const float* q    = (const float*)d_in[0];
  const float* k    = (const float*)d_in[1];
  const float* v    = (const float*)d_in[2];
  const int*   mask = (const int*)d_in[3];
  const float* pos  = (const float*)d_in[4];
  const float* qW   = (const float*)d_in[5];
  const float* kW   = (const float*)d_in[6];
  const float* vW   = (const float*)d_in[7];
  const float* pW   = (const float*)d_in[8];
  float* out = (float*)d_out;

  char* w = (char*)d_ws;
  const size_t MB = 1024 * 1024;
  // layout (59MB peak; proven rounds 15-17):
  //   Wt@0-8     (pWt@6-8 live to gemm_proj)
  //   Qp@8-16    (gemm_qkv -> attn3)
  //   Kpack@16-24 (gemm_qkv z==1 -> attn3)
  //   Vpk@24-32  (gemm_qkv z==2 -> attn3; V^T frags fs0-7, 1MB stride)
  //   Abf@32-56  (prep -> gemm_qkv, dead after)
  //   Mrow@56-58 (gemm_qkv z==2 -> attn3; mask rows fs8,9)
  //   Ptab@58-59 (prep -> gemm_qkv; RoPE cos/sin float2 table)
  //   X@32-40    over dead Abf head (attn3 -> gemm_proj)
  bf16*   Wt    = (bf16*)(w);
  bf16*   Qp    = (bf16*)(w + 8 * MB);
  bf16*   Kpack = (bf16*)(w + 16 * MB);
  bf16*   Vpk   = (bf16*)(w + 24 * MB);
  bf16*   Abf   = (bf16*)(w + 32 * MB);
  bf16*   Mrow  = (bf16*)(w + 56 * MB);
  float2* Ptab  = (float2*)(w + 58 * MB);
  bf16*   X     = (bf16*)(w + 32 * MB);

  prep<<<dim3(7680), 256, 0, stream>>>(qW, kW, vW, pW, q, k, v, pos,
                                       Wt, Abf, Ptab);
  gemm_qkv<<<dim3(768), 256, 0, stream>>>(Abf, Wt, Ptab, mask, Qp, Kpack, Vpk, Mrow);
  attn3<<<dim3(512), 256, 0, stream>>>(Qp, Kpack, Vpk, Mrow, X);
  gemm_proj<<<dim3(512), 256, 0, stream>>>(X, Wt + 3 * (size_t)CC * CC, out);
}